// Round 10
// baseline (1881.380 us; speedup 1.0000x reference)
//
#include <hip/hip_runtime.h>

#define F 128
#define H 64
#define O 16

#define BSHIFT 7
#define BSZ 128       // nodes per coarse bucket
#define NSUB 8        // privatized cursor sub-regions per bucket
#define SUBCAP 768    // capacity per (bucket,sub): mean 512, +11 sigma
#define ACHUNK 8192   // edges per bucketA block
#define XS 136        // gemm1 LDS row stride in f16
#define GSTR 67       // gatherA1 zacc row stride (floats): bank = 3d+8t+j, spread
#define GSTR2 17      // gatherA2 zacc row stride

typedef _Float16 half8_t __attribute__((ext_vector_type(8)));
typedef _Float16 half4_t __attribute__((ext_vector_type(4)));
typedef float f32x4 __attribute__((ext_vector_type(4)));

// ---------- CSR-free build: LDS-aggregated multisplit into buckets ----------
__global__ void k_bcur2(int* __restrict__ bcur, int NC) {
    int i = blockIdx.x * blockDim.x + threadIdx.x;
    if (i < NC) bcur[i] = i * SUBCAP;
}

__global__ __launch_bounds__(512) void k_bucketA(const int* __restrict__ src,
                                                 const int* __restrict__ dstv,
                                                 int* __restrict__ bcur,
                                                 int* __restrict__ bdata, int E) {
    __shared__ int hist[1024];
    for (int t = threadIdx.x; t < 1024; t += 512) hist[t] = 0;
    __syncthreads();
    int base = blockIdx.x * ACHUNK;
    int end = min(base + ACHUNK, E);
    for (int i = base + threadIdx.x; i < end; i += 512) {
        atomicAdd(&hist[dstv[i] >> BSHIFT], 1);
    }
    __syncthreads();
    int sub = blockIdx.x & (NSUB - 1);
    for (int b = threadIdx.x; b < 1024; b += 512) {
        int c = hist[b];
        if (c > 0) hist[b] = atomicAdd(&bcur[b * NSUB + sub], c);
    }
    __syncthreads();
    for (int i = base + threadIdx.x; i < end; i += 512) {
        int d = dstv[i];
        int b = d >> BSHIFT;
        int pos = atomicAdd(&hist[b], 1);
        bdata[pos] = (src[i] << BSHIFT) | (d & (BSZ - 1));
    }
}

// per-bucket degree histogram -> dis (deg array and scan eliminated)
__global__ __launch_bounds__(256) void k_bdeg(const int* __restrict__ bdata,
                                              const int* __restrict__ bcur,
                                              float* __restrict__ dis, int N) {
    __shared__ int h[BSZ];
    int b = blockIdx.x;
    int node0 = b << BSHIFT;
    int nloc = min(BSZ, N - node0);
    for (int t = threadIdx.x; t < BSZ; t += 256) h[t] = 0;
    __syncthreads();
    for (int s = 0; s < NSUB; s++) {
        int start = (b * NSUB + s) * SUBCAP;
        int end = bcur[b * NSUB + s];
        for (int p = start + threadIdx.x; p < end; p += 256)
            atomicAdd(&h[bdata[p] & (BSZ - 1)], 1);
    }
    __syncthreads();
    for (int t = threadIdx.x; t < nloc; t += 256)
        dis[node0 + t] = rsqrtf((float)h[t] + 1.0f);
}

// ---------- W1 prep: wt_hi/wt_lo = transposed fp16 hi/lo split, [n][k] ----------
__global__ void k_wprep(const float* __restrict__ W1, _Float16* __restrict__ wt_hi,
                        _Float16* __restrict__ wt_lo) {
    int idx = blockIdx.x * 256 + threadIdx.x;  // 64*128 = 8192
    int c = idx >> 7, k = idx & 127;
    float w = W1[k * H + c];
    _Float16 hi = (_Float16)w;
    wt_hi[idx] = hi;
    wt_lo[idx] = (_Float16)(w - (float)hi);
}

// ---------- layer 1: h1p = fp16( (x @ W1) * dis[row] ), MFMA hi/lo split ----------
__global__ __launch_bounds__(256) void k_gemm1(const float* __restrict__ x,
                                               const _Float16* __restrict__ wt_hi,
                                               const _Float16* __restrict__ wt_lo,
                                               const float* __restrict__ dis,
                                               _Float16* __restrict__ h1p, int N) {
    __shared__ _Float16 xh[64 * XS], xl[64 * XS], wh[64 * XS], wl[64 * XS];
    int tid = threadIdx.x;
    int row0 = blockIdx.x * 64;
#pragma unroll
    for (int i = 0; i < 8; i++) {
        int idx = i * 256 + tid;          // 2048 float4
        int r = idx >> 5;
        int c = (idx & 31) * 4;
        int rr = row0 + r; if (rr >= N) rr = N - 1;
        float4 v = *(const float4*)(x + (size_t)rr * F + c);
        half4_t h = {(_Float16)v.x, (_Float16)v.y, (_Float16)v.z, (_Float16)v.w};
        half4_t l = {(_Float16)(v.x - (float)h[0]), (_Float16)(v.y - (float)h[1]),
                     (_Float16)(v.z - (float)h[2]), (_Float16)(v.w - (float)h[3])};
        *(half4_t*)(xh + r * XS + c) = h;
        *(half4_t*)(xl + r * XS + c) = l;
    }
#pragma unroll
    for (int i = 0; i < 4; i++) {
        int idx = i * 256 + tid;          // 1024
        int c = idx >> 4;
        int k8 = (idx & 15) * 8;
        *(half8_t*)(wh + c * XS + k8) = *(const half8_t*)(wt_hi + c * 128 + k8);
        *(half8_t*)(wl + c * XS + k8) = *(const half8_t*)(wt_lo + c * 128 + k8);
    }
    __syncthreads();
    int wv = tid >> 6, lane = tid & 63;
    int m = lane & 15, qd = lane >> 4;
    const _Float16* xhp = xh + (wv * 16 + m) * XS;
    const _Float16* xlp = xl + (wv * 16 + m) * XS;
    f32x4 acc[4] = {f32x4{0,0,0,0}, f32x4{0,0,0,0}, f32x4{0,0,0,0}, f32x4{0,0,0,0}};
#pragma unroll
    for (int kc = 0; kc < 4; kc++) {
        int ko = kc * 32 + qd * 8;
        half8_t ah = *(const half8_t*)(xhp + ko);
        half8_t al = *(const half8_t*)(xlp + ko);
#pragma unroll
        for (int nt = 0; nt < 4; nt++) {
            half8_t bh = *(const half8_t*)(wh + (nt * 16 + m) * XS + ko);
            half8_t bl = *(const half8_t*)(wl + (nt * 16 + m) * XS + ko);
            acc[nt] = __builtin_amdgcn_mfma_f32_16x16x32_f16(ah, bh, acc[nt], 0, 0, 0);
            acc[nt] = __builtin_amdgcn_mfma_f32_16x16x32_f16(ah, bl, acc[nt], 0, 0, 0);
            acc[nt] = __builtin_amdgcn_mfma_f32_16x16x32_f16(al, bh, acc[nt], 0, 0, 0);
        }
    }
#pragma unroll
    for (int reg = 0; reg < 4; reg++) {
        int row = row0 + wv * 16 + qd * 4 + reg;
        if (row < N) {
            float d = dis[row];
#pragma unroll
            for (int nt = 0; nt < 4; nt++) {
                h1p[(size_t)row * H + nt * 16 + m] = (_Float16)(acc[nt][reg] * d);
            }
        }
    }
}

// ---------- layer 1 aggregation: per-bucket LDS accumulate from bdata ----------
// z[i] = relu( dis[i]*( sum_{s in N(i)} h1p[s] + h1p[i] ) + b1 )
__global__ __launch_bounds__(512) void k_gatherA1(const _Float16* __restrict__ h1p,
                                                  const float* __restrict__ dis,
                                                  const int* __restrict__ bdata,
                                                  const int* __restrict__ bcur,
                                                  const float* __restrict__ b1,
                                                  float* __restrict__ z, int N) {
    __shared__ float zacc[BSZ * GSTR];   // 34.3 KB
    int b = blockIdx.x;
    int tid = threadIdx.x;
    for (int i = tid; i < BSZ * GSTR; i += 512) zacc[i] = 0.f;
    __syncthreads();
    int gg = tid >> 3;       // edge group 0..63
    int t  = tid & 7;        // 16B slot within 128B row
    const half8_t* hp = (const half8_t*)h1p;
    for (int s = 0; s < NSUB; s++) {
        int start = (b * NSUB + s) * SUBCAP;
        int end = bcur[b * NSUB + s];
        int p = start + gg;
        // 2-deep pipeline: two independent row loads in flight per group
        for (; p + 64 < end; p += 128) {
            int v0 = bdata[p], v1 = bdata[p + 64];
            half8_t x0 = hp[(size_t)(v0 >> BSHIFT) * 8 + t];
            half8_t x1 = hp[(size_t)(v1 >> BSHIFT) * 8 + t];
            float* r0 = zacc + (v0 & (BSZ - 1)) * GSTR + t * 8;
            float* r1 = zacc + (v1 & (BSZ - 1)) * GSTR + t * 8;
#pragma unroll
            for (int j = 0; j < 8; j++) atomicAdd(&r0[j], (float)x0[j]);
#pragma unroll
            for (int j = 0; j < 8; j++) atomicAdd(&r1[j], (float)x1[j]);
        }
        if (p < end) {
            int v0 = bdata[p];
            half8_t x0 = hp[(size_t)(v0 >> BSHIFT) * 8 + t];
            float* r0 = zacc + (v0 & (BSZ - 1)) * GSTR + t * 8;
#pragma unroll
            for (int j = 0; j < 8; j++) atomicAdd(&r0[j], (float)x0[j]);
        }
    }
    __syncthreads();
    // epilogue: 4 threads/node, 16 feats each; fuse self + bias + relu + dn
    int node0 = blockIdx.x << BSHIFT;
    int d = tid >> 2;
    int q = tid & 3;
    int node = node0 + d;
    if (node < N) {
        float dn = dis[node];
        const float* za = zacc + d * GSTR + q * 16;
        half8_t s0 = hp[(size_t)node * 8 + q * 2];
        half8_t s1 = hp[(size_t)node * 8 + q * 2 + 1];
        float o[16];
#pragma unroll
        for (int j = 0; j < 8; j++)
            o[j] = fmaxf(fmaf(za[j] + (float)s0[j], dn, b1[q * 16 + j]), 0.f);
#pragma unroll
        for (int j = 0; j < 8; j++)
            o[8 + j] = fmaxf(fmaf(za[8 + j] + (float)s1[j], dn, b1[q * 16 + 8 + j]), 0.f);
        float4* zp = (float4*)(z + (size_t)node * H + q * 16);
#pragma unroll
        for (int i = 0; i < 4; i++)
            zp[i] = float4{o[i * 4], o[i * 4 + 1], o[i * 4 + 2], o[i * 4 + 3]};
    }
}

// ---------- layer 2: h2p = fp16( (z @ W2) * dis[row] ) ----------
__global__ __launch_bounds__(64) void k_gemm2(const float* __restrict__ z,
                                              const float* __restrict__ W2,
                                              const float* __restrict__ dis,
                                              _Float16* __restrict__ h2p, int N) {
    __shared__ float zs[64 * 65];
    int lane = threadIdx.x;
    int row0 = blockIdx.x * 64;
#pragma unroll
    for (int i = 0; i < 16; i++) {
        int r = i * 4 + (lane >> 4);
        int c = (lane & 15) * 4;
        int rr = row0 + r; if (rr >= N) rr = N - 1;
        float4 v = *(const float4*)(z + (size_t)rr * H + c);
        zs[r * 65 + c + 0] = v.x;
        zs[r * 65 + c + 1] = v.y;
        zs[r * 65 + c + 2] = v.z;
        zs[r * 65 + c + 3] = v.w;
    }
    __syncthreads();
    float acc[O];
#pragma unroll
    for (int c = 0; c < O; c++) acc[c] = 0.f;
#pragma unroll 4
    for (int k = 0; k < H; k++) {
        float a = zs[lane * 65 + k];
        const float* wrow = W2 + (size_t)k * O;  // uniform in k -> s_load
#pragma unroll
        for (int c = 0; c < O; c++) acc[c] = fmaf(a, wrow[c], acc[c]);
    }
    int row = row0 + lane;
    if (row < N) {
        float d = dis[row];
        half8_t* orow = (half8_t*)(h2p + (size_t)row * O);
#pragma unroll
        for (int c0 = 0; c0 < O; c0 += 8) {
            half8_t o;
#pragma unroll
            for (int j = 0; j < 8; j++) o[j] = (_Float16)(acc[c0 + j] * d);
            orow[c0 / 8] = o;
        }
    }
}

// ---------- layer 2 aggregation: per-bucket LDS accumulate ----------
__global__ __launch_bounds__(512) void k_gatherA2(const _Float16* __restrict__ h2p,
                                                  const float* __restrict__ dis,
                                                  const int* __restrict__ bdata,
                                                  const int* __restrict__ bcur,
                                                  const float* __restrict__ b2,
                                                  float* __restrict__ z2, int N) {
    __shared__ float zacc[BSZ * GSTR2];  // 8.7 KB
    int b = blockIdx.x;
    int tid = threadIdx.x;
    for (int i = tid; i < BSZ * GSTR2; i += 512) zacc[i] = 0.f;
    __syncthreads();
    int gg = tid >> 1;       // edge group 0..255
    int t  = tid & 1;        // 16B slot within 32B row
    const half8_t* hp = (const half8_t*)h2p;
    for (int s = 0; s < NSUB; s++) {
        int start = (b * NSUB + s) * SUBCAP;
        int end = bcur[b * NSUB + s];
        int p = start + gg;
        for (; p + 256 < end; p += 512) {
            int v0 = bdata[p], v1 = bdata[p + 256];
            half8_t x0 = hp[(size_t)(v0 >> BSHIFT) * 2 + t];
            half8_t x1 = hp[(size_t)(v1 >> BSHIFT) * 2 + t];
            float* r0 = zacc + (v0 & (BSZ - 1)) * GSTR2 + t * 8;
            float* r1 = zacc + (v1 & (BSZ - 1)) * GSTR2 + t * 8;
#pragma unroll
            for (int j = 0; j < 8; j++) atomicAdd(&r0[j], (float)x0[j]);
#pragma unroll
            for (int j = 0; j < 8; j++) atomicAdd(&r1[j], (float)x1[j]);
        }
        if (p < end) {
            int v0 = bdata[p];
            half8_t x0 = hp[(size_t)(v0 >> BSHIFT) * 2 + t];
            float* r0 = zacc + (v0 & (BSZ - 1)) * GSTR2 + t * 8;
#pragma unroll
            for (int j = 0; j < 8; j++) atomicAdd(&r0[j], (float)x0[j]);
        }
    }
    __syncthreads();
    // epilogue: 4 threads/node, 4 feats each
    int node0 = blockIdx.x << BSHIFT;
    int d = tid >> 2;
    int q = tid & 3;
    int node = node0 + d;
    if (node < N) {
        float dn = dis[node];
        const float* za = zacc + d * GSTR2 + q * 4;
        half4_t self = *(const half4_t*)(h2p + (size_t)node * O + q * 4);
        float4 o;
        o.x = fmaf(za[0] + (float)self[0], dn, b2[q * 4 + 0]);
        o.y = fmaf(za[1] + (float)self[1], dn, b2[q * 4 + 1]);
        o.z = fmaf(za[2] + (float)self[2], dn, b2[q * 4 + 2]);
        o.w = fmaf(za[3] + (float)self[3], dn, b2[q * 4 + 3]);
        *(float4*)(z2 + (size_t)node * O + q * 4) = o;
    }
}

// ---------- link prediction logits: 4 lanes per pair ----------
__global__ __launch_bounds__(256) void k_logits(const float* __restrict__ z2,
                                                const int* __restrict__ pos,
                                                const int* __restrict__ neg,
                                                float* __restrict__ out, int P, int Q) {
    int tid = blockIdx.x * 256 + threadIdx.x;
    int i = tid >> 2;
    if (i >= P + Q) return;
    int k = tid & 3;
    int a, b;
    if (i < P) { a = pos[i]; b = pos[P + i]; }
    else       { int t = i - P; a = neg[t]; b = neg[Q + t]; }
    float4 va = *(const float4*)(z2 + (size_t)a * O + k * 4);
    float4 vb = *(const float4*)(z2 + (size_t)b * O + k * 4);
    float r = va.x * vb.x + va.y * vb.y + va.z * vb.z + va.w * vb.w;
    r += __shfl_xor(r, 1);
    r += __shfl_xor(r, 2);
    if (k == 0) out[i] = r;
}

extern "C" void kernel_launch(void* const* d_in, const int* in_sizes, int n_in,
                              void* d_out, int out_size, void* d_ws, size_t ws_size,
                              hipStream_t stream) {
    const float* x   = (const float*)d_in[0];
    const int*   ei  = (const int*)d_in[1];
    const int*   pos = (const int*)d_in[2];
    const int*   neg = (const int*)d_in[3];
    const float* W1  = (const float*)d_in[4];
    const float* b1  = (const float*)d_in[5];
    const float* W2  = (const float*)d_in[6];
    const float* b2  = (const float*)d_in[7];
    float* out = (float*)d_out;

    int N = in_sizes[0] / F;
    int E = in_sizes[1] / 2;
    int P = in_sizes[2] / 2;
    int Q = in_sizes[3] / 2;
    const int* src  = ei;
    const int* dstv = ei + E;

    int Npad = ((N + 255) / 256) * 256;
    int NBK = (N + BSZ - 1) / BSZ;    // coarse buckets (782)
    int NC  = NBK * NSUB;             // privatized cursors

    // workspace layout (byte-exact; no aliasing — bdata is live through gathers)
    char* w = (char*)d_ws;
    float*    dis   = (float*)w;      w += (size_t)Npad * 4;
    int*      bcur  = (int*)w;        w += 8192 * 4;            // NC <= 8192
    int*      bdata = (int*)w;        w += (size_t)NC * SUBCAP * 4;  // 19.2MB
    _Float16* h1p   = (_Float16*)w;   w += (size_t)N * H * 2;   // 12.8MB
    float*    z     = (float*)w;      w += (size_t)N * H * 4;   // 25.6MB
    _Float16* h2p   = (_Float16*)w;   w += (size_t)N * O * 2;   // 3.2MB
    float*    z2    = (float*)w;      w += (size_t)N * O * 4;   // 6.4MB
    _Float16* wt_hi = (_Float16*)w;   w += (size_t)H * F * 2;   // 16KB
    _Float16* wt_lo = (_Float16*)w;

    // prep + bucket build (no CSR, no scans, no col)
    k_wprep<<<(H * F + 255) / 256, 256, 0, stream>>>(W1, wt_hi, wt_lo);
    k_bcur2<<<(NC + 255) / 256, 256, 0, stream>>>(bcur, NC);
    k_bucketA<<<(E + ACHUNK - 1) / ACHUNK, 512, 0, stream>>>(src, dstv, bcur, bdata, E);
    k_bdeg<<<NBK, 256, 0, stream>>>(bdata, bcur, dis, N);

    // layer 1
    k_gemm1<<<(N + 63) / 64, 256, 0, stream>>>(x, wt_hi, wt_lo, dis, h1p, N);
    k_gatherA1<<<NBK, 512, 0, stream>>>(h1p, dis, bdata, bcur, b1, z, N);

    // layer 2
    k_gemm2<<<(N + 63) / 64, 64, 0, stream>>>(z, W2, dis, h2p, N);
    k_gatherA2<<<NBK, 512, 0, stream>>>(h2p, dis, bdata, bcur, b2, z2, N);

    // logits
    k_logits<<<((P + Q) * 4 + 255) / 256, 256, 0, stream>>>(z2, pos, neg, out, P, Q);
}

// Round 11
// 330.460 us; speedup vs baseline: 5.6932x; 5.6932x over previous
//
#include <hip/hip_runtime.h>

#define F 128
#define H 64
#define O 16

#define BSHIFT 7
#define BSZ 128       // nodes per coarse bucket
#define NSUB 8        // privatized cursor sub-regions per bucket
#define SUBCAP 768    // capacity per (bucket,sub): mean ~513, +11 sigma
#define ACHUNK 8192   // edges per bucketA block
#define XS 136        // gemm1 LDS row stride in f16

typedef _Float16 half8_t __attribute__((ext_vector_type(8)));
typedef _Float16 half4_t __attribute__((ext_vector_type(4)));
typedef float f32x4 __attribute__((ext_vector_type(4)));

// ---------- bucket build: LDS-aggregated multisplit, privatized reservation ----------
__global__ void k_bcur2(int* __restrict__ bcur, int NC) {
    int i = blockIdx.x * blockDim.x + threadIdx.x;
    if (i < NC) bcur[i] = i * SUBCAP;
}

__global__ __launch_bounds__(512) void k_bucketA(const int* __restrict__ src,
                                                 const int* __restrict__ dstv,
                                                 int* __restrict__ bcur,
                                                 int* __restrict__ bdata, int E) {
    __shared__ int hist[1024];
    for (int t = threadIdx.x; t < 1024; t += 512) hist[t] = 0;
    __syncthreads();
    int base = blockIdx.x * ACHUNK;
    int end = min(base + ACHUNK, E);
    for (int i = base + threadIdx.x; i < end; i += 512) {
        atomicAdd(&hist[dstv[i] >> BSHIFT], 1);
    }
    __syncthreads();
    int sub = blockIdx.x & (NSUB - 1);
    for (int b = threadIdx.x; b < 1024; b += 512) {
        int c = hist[b];
        if (c > 0) hist[b] = atomicAdd(&bcur[b * NSUB + sub], c);
    }
    __syncthreads();
    for (int i = base + threadIdx.x; i < end; i += 512) {
        int d = dstv[i];
        int b = d >> BSHIFT;
        int pos = atomicAdd(&hist[b], 1);
        bdata[pos] = (src[i] << BSHIFT) | (d & (BSZ - 1));
    }
}

// per-bucket degree histogram -> deg (coalesced) + dis (fused; k_dis eliminated)
__global__ __launch_bounds__(256) void k_bdeg(const int* __restrict__ bdata,
                                              const int* __restrict__ bcur,
                                              int* __restrict__ deg,
                                              float* __restrict__ dis, int N) {
    __shared__ int h[BSZ];
    int b = blockIdx.x;
    int node0 = b << BSHIFT;
    int nloc = min(BSZ, N - node0);
    for (int t = threadIdx.x; t < BSZ; t += 256) h[t] = 0;
    __syncthreads();
    for (int s = 0; s < NSUB; s++) {
        int start = (b * NSUB + s) * SUBCAP;
        int end = bcur[b * NSUB + s];
        for (int p = start + threadIdx.x; p < end; p += 256)
            atomicAdd(&h[bdata[p] & (BSZ - 1)], 1);
    }
    __syncthreads();
    for (int t = threadIdx.x; t < nloc; t += 256) {
        int d = h[t];
        deg[node0 + t] = d;
        dis[node0 + t] = rsqrtf((float)d + 1.0f);
    }
}

// 1-block scan over bucket totals (782 values; replaces the 100K-element scan chain)
__global__ void k_bscan(const int* __restrict__ bcur, int* __restrict__ bstart, int NBK) {
    __shared__ int s[1024];
    int tid = threadIdx.x;
    int tot = 0;
    if (tid < NBK) {
        for (int ss = 0; ss < NSUB; ss++)
            tot += bcur[tid * NSUB + ss] - (tid * NSUB + ss) * SUBCAP;
    }
    s[tid] = tot;
    __syncthreads();
    for (int off = 1; off < 1024; off <<= 1) {
        int v = (tid >= off) ? s[tid - off] : 0;
        __syncthreads();
        s[tid] += v;
        __syncthreads();
    }
    bstart[tid] = s[tid] - tot;  // exclusive
}

// per-bucket: local 128-scan of deg -> row_ptr (coalesced) + exact CSR placement
__global__ __launch_bounds__(256) void k_bplace(const int* __restrict__ bdata,
                                                const int* __restrict__ bcur,
                                                const int* __restrict__ deg,
                                                const int* __restrict__ bstart,
                                                int* __restrict__ row_ptr,
                                                int* __restrict__ col, int N) {
    __shared__ int pref[BSZ];
    __shared__ int cur[BSZ];
    int b = blockIdx.x;
    int node0 = b << BSHIFT;
    int nloc = min(BSZ, N - node0);
    int tid = threadIdx.x;
    int myDeg = 0;
    if (tid < BSZ) {
        myDeg = (tid < nloc) ? deg[node0 + tid] : 0;
        pref[tid] = myDeg;
    }
    __syncthreads();
    // Hillis-Steele inclusive scan over 128
    for (int off = 1; off < BSZ; off <<= 1) {
        int v = (tid < BSZ && tid >= off) ? pref[tid - off] : 0;
        __syncthreads();
        if (tid < BSZ) pref[tid] += v;
        __syncthreads();
    }
    int base = bstart[b];
    if (tid < nloc) {
        int excl = base + pref[tid] - myDeg;
        cur[tid] = excl;
        row_ptr[node0 + tid] = excl;
    }
    if (tid == 0) row_ptr[node0 + nloc] = base + pref[BSZ - 1];  // bucket end (idempotent)
    __syncthreads();
    for (int s = 0; s < NSUB; s++) {
        int start = (b * NSUB + s) * SUBCAP;
        int end = bcur[b * NSUB + s];
        for (int p = start + tid; p < end; p += 256) {
            int v = bdata[p];
            int pos = atomicAdd(&cur[v & (BSZ - 1)], 1);
            col[pos] = v >> BSHIFT;
        }
    }
}

// ---------- W1 prep: wt_hi/wt_lo = transposed fp16 hi/lo split, [n][k] ----------
__global__ void k_wprep(const float* __restrict__ W1, _Float16* __restrict__ wt_hi,
                        _Float16* __restrict__ wt_lo) {
    int idx = blockIdx.x * 256 + threadIdx.x;  // 64*128 = 8192
    int c = idx >> 7, k = idx & 127;
    float w = W1[k * H + c];
    _Float16 hi = (_Float16)w;
    wt_hi[idx] = hi;
    wt_lo[idx] = (_Float16)(w - (float)hi);
}

// ---------- layer 1: h1p = fp16( (x @ W1) * dis[row] ), MFMA hi/lo split ----------
__global__ __launch_bounds__(256) void k_gemm1(const float* __restrict__ x,
                                               const _Float16* __restrict__ wt_hi,
                                               const _Float16* __restrict__ wt_lo,
                                               const float* __restrict__ dis,
                                               _Float16* __restrict__ h1p, int N) {
    __shared__ _Float16 xh[64 * XS], xl[64 * XS], wh[64 * XS], wl[64 * XS];
    int tid = threadIdx.x;
    int row0 = blockIdx.x * 64;
#pragma unroll
    for (int i = 0; i < 8; i++) {
        int idx = i * 256 + tid;          // 2048 float4
        int r = idx >> 5;
        int c = (idx & 31) * 4;
        int rr = row0 + r; if (rr >= N) rr = N - 1;
        float4 v = *(const float4*)(x + (size_t)rr * F + c);
        half4_t h = {(_Float16)v.x, (_Float16)v.y, (_Float16)v.z, (_Float16)v.w};
        half4_t l = {(_Float16)(v.x - (float)h[0]), (_Float16)(v.y - (float)h[1]),
                     (_Float16)(v.z - (float)h[2]), (_Float16)(v.w - (float)h[3])};
        *(half4_t*)(xh + r * XS + c) = h;
        *(half4_t*)(xl + r * XS + c) = l;
    }
#pragma unroll
    for (int i = 0; i < 4; i++) {
        int idx = i * 256 + tid;          // 1024
        int c = idx >> 4;
        int k8 = (idx & 15) * 8;
        *(half8_t*)(wh + c * XS + k8) = *(const half8_t*)(wt_hi + c * 128 + k8);
        *(half8_t*)(wl + c * XS + k8) = *(const half8_t*)(wt_lo + c * 128 + k8);
    }
    __syncthreads();
    int wv = tid >> 6, lane = tid & 63;
    int m = lane & 15, qd = lane >> 4;
    const _Float16* xhp = xh + (wv * 16 + m) * XS;
    const _Float16* xlp = xl + (wv * 16 + m) * XS;
    f32x4 acc[4] = {f32x4{0,0,0,0}, f32x4{0,0,0,0}, f32x4{0,0,0,0}, f32x4{0,0,0,0}};
#pragma unroll
    for (int kc = 0; kc < 4; kc++) {
        int ko = kc * 32 + qd * 8;
        half8_t ah = *(const half8_t*)(xhp + ko);
        half8_t al = *(const half8_t*)(xlp + ko);
#pragma unroll
        for (int nt = 0; nt < 4; nt++) {
            half8_t bh = *(const half8_t*)(wh + (nt * 16 + m) * XS + ko);
            half8_t bl = *(const half8_t*)(wl + (nt * 16 + m) * XS + ko);
            acc[nt] = __builtin_amdgcn_mfma_f32_16x16x32_f16(ah, bh, acc[nt], 0, 0, 0);
            acc[nt] = __builtin_amdgcn_mfma_f32_16x16x32_f16(ah, bl, acc[nt], 0, 0, 0);
            acc[nt] = __builtin_amdgcn_mfma_f32_16x16x32_f16(al, bh, acc[nt], 0, 0, 0);
        }
    }
#pragma unroll
    for (int reg = 0; reg < 4; reg++) {
        int row = row0 + wv * 16 + qd * 4 + reg;
        if (row < N) {
            float d = dis[row];
#pragma unroll
            for (int nt = 0; nt < 4; nt++) {
                h1p[(size_t)row * H + nt * 16 + m] = (_Float16)(acc[nt][reg] * d);
            }
        }
    }
}

// ---------- layer 1 aggregation: 1 wave/node, 16 rows in flight (unroll 2) ----------
__global__ __launch_bounds__(256) void k_gather1(const _Float16* __restrict__ h1p,
                                                 const float* __restrict__ dis,
                                                 const int* __restrict__ row_ptr,
                                                 const int* __restrict__ col,
                                                 const float* __restrict__ b1,
                                                 float* __restrict__ z, int N) {
    int node = blockIdx.x * 4 + (threadIdx.x >> 6);
    if (node >= N) return;
    int lane = threadIdx.x & 63;
    int g = lane >> 3;   // edge group 0..7
    int t = lane & 7;    // 16B slot
    const half8_t* hp = (const half8_t*)h1p;
    float acc[8];
#pragma unroll
    for (int j = 0; j < 8; j++) acc[j] = 0.f;
    int e = row_ptr[node + 1];
    int p = row_ptr[node] + g;
    for (; p + 8 < e; p += 16) {   // 2 independent row loads in flight per group
        int s0 = col[p], s1 = col[p + 8];
        half8_t v0 = hp[(size_t)s0 * 8 + t];
        half8_t v1 = hp[(size_t)s1 * 8 + t];
#pragma unroll
        for (int j = 0; j < 8; j++) acc[j] += (float)v0[j];
#pragma unroll
        for (int j = 0; j < 8; j++) acc[j] += (float)v1[j];
    }
    if (p < e) {
        int s0 = col[p];
        half8_t v0 = hp[(size_t)s0 * 8 + t];
#pragma unroll
        for (int j = 0; j < 8; j++) acc[j] += (float)v0[j];
    }
#pragma unroll
    for (int off = 8; off < 64; off <<= 1) {
#pragma unroll
        for (int j = 0; j < 8; j++) acc[j] += __shfl_xor(acc[j], off);
    }
    if (g == 0) {
        float dn = dis[node];
        half8_t self = hp[(size_t)node * 8 + t];
        float o[8];
#pragma unroll
        for (int j = 0; j < 8; j++)
            o[j] = fmaxf(fmaf(acc[j] + (float)self[j], dn, b1[t * 8 + j]), 0.f);
        float4* zp = (float4*)(z + (size_t)node * H + t * 8);
        zp[0] = float4{o[0], o[1], o[2], o[3]};
        zp[1] = float4{o[4], o[5], o[6], o[7]};
    }
}

// ---------- layer 2: h2p = fp16( (z @ W2) * dis[row] ) ----------
__global__ __launch_bounds__(64) void k_gemm2(const float* __restrict__ z,
                                              const float* __restrict__ W2,
                                              const float* __restrict__ dis,
                                              _Float16* __restrict__ h2p, int N) {
    __shared__ float zs[64 * 65];
    int lane = threadIdx.x;
    int row0 = blockIdx.x * 64;
#pragma unroll
    for (int i = 0; i < 16; i++) {
        int r = i * 4 + (lane >> 4);
        int c = (lane & 15) * 4;
        int rr = row0 + r; if (rr >= N) rr = N - 1;
        float4 v = *(const float4*)(z + (size_t)rr * H + c);
        zs[r * 65 + c + 0] = v.x;
        zs[r * 65 + c + 1] = v.y;
        zs[r * 65 + c + 2] = v.z;
        zs[r * 65 + c + 3] = v.w;
    }
    __syncthreads();
    float acc[O];
#pragma unroll
    for (int c = 0; c < O; c++) acc[c] = 0.f;
#pragma unroll 4
    for (int k = 0; k < H; k++) {
        float a = zs[lane * 65 + k];
        const float* wrow = W2 + (size_t)k * O;  // uniform in k -> s_load
#pragma unroll
        for (int c = 0; c < O; c++) acc[c] = fmaf(a, wrow[c], acc[c]);
    }
    int row = row0 + lane;
    if (row < N) {
        float d = dis[row];
        half8_t* orow = (half8_t*)(h2p + (size_t)row * O);
#pragma unroll
        for (int c0 = 0; c0 < O; c0 += 8) {
            half8_t o;
#pragma unroll
            for (int j = 0; j < 8; j++) o[j] = (_Float16)(acc[c0 + j] * d);
            orow[c0 / 8] = o;
        }
    }
}

// ---------- layer 2 aggregation: 1 wave/node, 32 edges in flight, fp16 rows ----------
__global__ __launch_bounds__(256) void k_gather2(const _Float16* __restrict__ h2p,
                                                 const float* __restrict__ dis,
                                                 const int* __restrict__ row_ptr,
                                                 const int* __restrict__ col,
                                                 const float* __restrict__ b2,
                                                 float* __restrict__ z2, int N) {
    int node = blockIdx.x * 4 + (threadIdx.x >> 6);
    if (node >= N) return;
    int lane = threadIdx.x & 63;
    int g = lane >> 1;   // edge group 0..31
    int t = lane & 1;    // 16B slot
    const half8_t* hp = (const half8_t*)h2p;
    float acc[8];
#pragma unroll
    for (int j = 0; j < 8; j++) acc[j] = 0.f;
    int e = row_ptr[node + 1];
    for (int p = row_ptr[node] + g; p < e; p += 32) {
        int s = col[p];
        half8_t v = hp[(size_t)s * 2 + t];
#pragma unroll
        for (int j = 0; j < 8; j++) acc[j] += (float)v[j];
    }
#pragma unroll
    for (int off = 2; off < 64; off <<= 1) {
#pragma unroll
        for (int j = 0; j < 8; j++) acc[j] += __shfl_xor(acc[j], off);
    }
    if (g == 0) {
        float dn = dis[node];
        half8_t self = hp[(size_t)node * 2 + t];
        float o[8];
#pragma unroll
        for (int j = 0; j < 8; j++)
            o[j] = fmaf(acc[j] + (float)self[j], dn, b2[t * 8 + j]);
        float4* zp = (float4*)(z2 + (size_t)node * O + t * 8);
        zp[0] = float4{o[0], o[1], o[2], o[3]};
        zp[1] = float4{o[4], o[5], o[6], o[7]};
    }
}

// ---------- link prediction logits: 4 lanes per pair ----------
__global__ __launch_bounds__(256) void k_logits(const float* __restrict__ z2,
                                                const int* __restrict__ pos,
                                                const int* __restrict__ neg,
                                                float* __restrict__ out, int P, int Q) {
    int tid = blockIdx.x * 256 + threadIdx.x;
    int i = tid >> 2;
    if (i >= P + Q) return;
    int k = tid & 3;
    int a, b;
    if (i < P) { a = pos[i]; b = pos[P + i]; }
    else       { int t = i - P; a = neg[t]; b = neg[Q + t]; }
    float4 va = *(const float4*)(z2 + (size_t)a * O + k * 4);
    float4 vb = *(const float4*)(z2 + (size_t)b * O + k * 4);
    float r = va.x * vb.x + va.y * vb.y + va.z * vb.z + va.w * vb.w;
    r += __shfl_xor(r, 1);
    r += __shfl_xor(r, 2);
    if (k == 0) out[i] = r;
}

extern "C" void kernel_launch(void* const* d_in, const int* in_sizes, int n_in,
                              void* d_out, int out_size, void* d_ws, size_t ws_size,
                              hipStream_t stream) {
    const float* x   = (const float*)d_in[0];
    const int*   ei  = (const int*)d_in[1];
    const int*   pos = (const int*)d_in[2];
    const int*   neg = (const int*)d_in[3];
    const float* W1  = (const float*)d_in[4];
    const float* b1  = (const float*)d_in[5];
    const float* W2  = (const float*)d_in[6];
    const float* b2  = (const float*)d_in[7];
    float* out = (float*)d_out;

    int N = in_sizes[0] / F;
    int E = in_sizes[1] / 2;
    int P = in_sizes[2] / 2;
    int Q = in_sizes[3] / 2;
    const int* src  = ei;
    const int* dstv = ei + E;

    int Npad = ((N + 255) / 256) * 256;
    int Epad = (E + 63) & ~63;
    int NBK = (N + BSZ - 1) / BSZ;    // coarse buckets (782)
    int NC  = NBK * NSUB;             // privatized cursors

    // workspace layout (byte-exact; bdata aliases h1p — dead before k_gemm1 writes)
    char* w = (char*)d_ws;
    int*      deg   = (int*)w;        w += (size_t)Npad * 4;
    float*    dis   = (float*)w;      w += (size_t)Npad * 4;
    int*      row_ptr = (int*)w;      w += (size_t)(Npad + 256) * 4;
    int*      bcur  = (int*)w;        w += 8192 * 4;            // NC <= 8192
    int*      bstart = (int*)w;       w += 1024 * 4;
    int*      col   = (int*)w;        w += (size_t)Epad * 4;
    _Float16* h1p   = (_Float16*)w;
    int*      bdata = (int*)w;
    size_t h1b = (size_t)N * H * 2, bdb = (size_t)NC * SUBCAP * 4;
    w += (h1b > bdb ? h1b : bdb);
    float*    z     = (float*)w;      w += (size_t)N * H * 4;
    _Float16* h2p   = (_Float16*)w;   w += (size_t)N * O * 2;
    float*    z2    = (float*)w;      w += (size_t)N * O * 4;
    _Float16* wt_hi = (_Float16*)w;   w += (size_t)H * F * 2;   // 16KB
    _Float16* wt_lo = (_Float16*)w;

    // prep + bucket build + bucket-level CSR (no N-sized scans)
    k_wprep<<<(H * F + 255) / 256, 256, 0, stream>>>(W1, wt_hi, wt_lo);
    k_bcur2<<<(NC + 255) / 256, 256, 0, stream>>>(bcur, NC);
    k_bucketA<<<(E + ACHUNK - 1) / ACHUNK, 512, 0, stream>>>(src, dstv, bcur, bdata, E);
    k_bdeg<<<NBK, 256, 0, stream>>>(bdata, bcur, deg, dis, N);
    k_bscan<<<1, 1024, 0, stream>>>(bcur, bstart, NBK);
    k_bplace<<<NBK, 256, 0, stream>>>(bdata, bcur, deg, bstart, row_ptr, col, N);

    // layer 1
    k_gemm1<<<(N + 63) / 64, 256, 0, stream>>>(x, wt_hi, wt_lo, dis, h1p, N);
    k_gather1<<<(N + 3) / 4, 256, 0, stream>>>(h1p, dis, row_ptr, col, b1, z, N);

    // layer 2
    k_gemm2<<<(N + 63) / 64, 64, 0, stream>>>(z, W2, dis, h2p, N);
    k_gather2<<<(N + 3) / 4, 256, 0, stream>>>(h2p, dis, row_ptr, col, b2, z2, N);

    // logits
    k_logits<<<((P + Q) * 4 + 255) / 256, 256, 0, stream>>>(z2, pos, neg, out, P, Q);
}

// Round 12
// 328.103 us; speedup vs baseline: 5.7341x; 1.0072x over previous
//
#include <hip/hip_runtime.h>

#define F 128
#define H 64
#define O 16

#define BSHIFT 7
#define BSZ 128       // nodes per coarse bucket
#define NSUB 16       // privatized cursor sub-regions per bucket
#define SUBCAP 384    // capacity per (bucket,sub): mean 256, +8 sigma
#define ACHUNK 8192   // edges per bucketA block
#define XS 136        // gemm1 LDS row stride in f16

typedef _Float16 half8_t __attribute__((ext_vector_type(8)));
typedef _Float16 half4_t __attribute__((ext_vector_type(4)));
typedef float f32x4 __attribute__((ext_vector_type(4)));

// ---------- prep: W1 hi/lo transpose split + cursor init (merged) ----------
__global__ void k_prep(const float* __restrict__ W1, _Float16* __restrict__ wt_hi,
                       _Float16* __restrict__ wt_lo, int* __restrict__ bcur, int NC) {
    int i = blockIdx.x * blockDim.x + threadIdx.x;
    if (i < NC) bcur[i] = i * SUBCAP;
    if (i < H * F) {
        int c = i >> 7, k = i & 127;
        float w = W1[k * H + c];
        _Float16 hi = (_Float16)w;
        wt_hi[i] = hi;
        wt_lo[i] = (_Float16)(w - (float)hi);
    }
}

// ---------- bucket build: LDS-aggregated multisplit, privatized reservation ----------
__global__ __launch_bounds__(512) void k_bucketA(const int* __restrict__ src,
                                                 const int* __restrict__ dstv,
                                                 int* __restrict__ bcur,
                                                 int* __restrict__ bdata, int E) {
    __shared__ int hist[1024];
    for (int t = threadIdx.x; t < 1024; t += 512) hist[t] = 0;
    __syncthreads();
    int base = blockIdx.x * ACHUNK;
    int end = min(base + ACHUNK, E);
    int tid = threadIdx.x;
    // pass 1: histogram (int4 reads)
    for (int i = base + tid * 4; i + 3 < end; i += 2048) {
        int4 d4 = *(const int4*)(dstv + i);
        atomicAdd(&hist[d4.x >> BSHIFT], 1);
        atomicAdd(&hist[d4.y >> BSHIFT], 1);
        atomicAdd(&hist[d4.z >> BSHIFT], 1);
        atomicAdd(&hist[d4.w >> BSHIFT], 1);
    }
    for (int i = base + ((end - base) & ~3) + tid; i < end; i += 512)
        atomicAdd(&hist[dstv[i] >> BSHIFT], 1);
    __syncthreads();
    // reserve ranges in this block's private sub-region cursors
    int sub = blockIdx.x & (NSUB - 1);
    for (int b = tid; b < 1024; b += 512) {
        int c = hist[b];
        if (c > 0) hist[b] = atomicAdd(&bcur[b * NSUB + sub], c);
    }
    __syncthreads();
    // pass 2: place packed (src<<7 | local_dst) via LDS cursors
    for (int i = base + tid * 4; i + 3 < end; i += 2048) {
        int4 s4 = *(const int4*)(src + i);
        int4 d4 = *(const int4*)(dstv + i);
        int p0 = atomicAdd(&hist[d4.x >> BSHIFT], 1);
        bdata[p0] = (s4.x << BSHIFT) | (d4.x & (BSZ - 1));
        int p1 = atomicAdd(&hist[d4.y >> BSHIFT], 1);
        bdata[p1] = (s4.y << BSHIFT) | (d4.y & (BSZ - 1));
        int p2 = atomicAdd(&hist[d4.z >> BSHIFT], 1);
        bdata[p2] = (s4.z << BSHIFT) | (d4.z & (BSZ - 1));
        int p3 = atomicAdd(&hist[d4.w >> BSHIFT], 1);
        bdata[p3] = (s4.w << BSHIFT) | (d4.w & (BSZ - 1));
    }
    for (int i = base + ((end - base) & ~3) + tid; i < end; i += 512) {
        int d = dstv[i];
        int pos = atomicAdd(&hist[d >> BSHIFT], 1);
        bdata[pos] = (src[i] << BSHIFT) | (d & (BSZ - 1));
    }
}

// 1-block scan over bucket totals (from bcur deltas)
__global__ void k_bscan(const int* __restrict__ bcur, int* __restrict__ bstart, int NBK) {
    __shared__ int s[1024];
    int tid = threadIdx.x;
    int tot = 0;
    if (tid < NBK) {
        for (int ss = 0; ss < NSUB; ss++)
            tot += bcur[tid * NSUB + ss] - (tid * NSUB + ss) * SUBCAP;
    }
    s[tid] = tot;
    __syncthreads();
    for (int off = 1; off < 1024; off <<= 1) {
        int v = (tid >= off) ? s[tid - off] : 0;
        __syncthreads();
        s[tid] += v;
        __syncthreads();
    }
    bstart[tid] = s[tid] - tot;  // exclusive
}

// per-bucket: histogram + local scan -> row_ptr + dis + exact CSR placement
// (bdeg merged in; bucket's bdata stays L2-hot between the two passes)
__global__ __launch_bounds__(256) void k_bplace(const int* __restrict__ bdata,
                                                const int* __restrict__ bcur,
                                                const int* __restrict__ bstart,
                                                int* __restrict__ row_ptr,
                                                float* __restrict__ dis,
                                                int* __restrict__ col, int N) {
    __shared__ int h[BSZ];
    __shared__ int pref[BSZ];
    __shared__ int cur[BSZ];
    int b = blockIdx.x;
    int node0 = b << BSHIFT;
    int nloc = min(BSZ, N - node0);
    int tid = threadIdx.x;
    if (tid < BSZ) h[tid] = 0;
    __syncthreads();
    // pass 1: per-bucket degree histogram
    for (int s = 0; s < NSUB; s++) {
        int start = (b * NSUB + s) * SUBCAP;
        int end = bcur[b * NSUB + s];
        for (int p = start + tid; p < end; p += 256)
            atomicAdd(&h[bdata[p] & (BSZ - 1)], 1);
    }
    __syncthreads();
    int myDeg = 0;
    if (tid < BSZ) {
        myDeg = h[tid];
        pref[tid] = myDeg;
    }
    __syncthreads();
    // Hillis-Steele inclusive scan over 128
    for (int off = 1; off < BSZ; off <<= 1) {
        int v = (tid < BSZ && tid >= off) ? pref[tid - off] : 0;
        __syncthreads();
        if (tid < BSZ) pref[tid] += v;
        __syncthreads();
    }
    int base = bstart[b];
    if (tid < nloc) {
        int excl = base + pref[tid] - myDeg;
        cur[tid] = excl;
        row_ptr[node0 + tid] = excl;
        dis[node0 + tid] = rsqrtf((float)myDeg + 1.0f);
    }
    if (tid == 0) row_ptr[node0 + nloc] = base + pref[BSZ - 1];
    __syncthreads();
    // pass 2: exact placement (stores confined to bucket's L2-hot window)
    for (int s = 0; s < NSUB; s++) {
        int start = (b * NSUB + s) * SUBCAP;
        int end = bcur[b * NSUB + s];
        for (int p = start + tid; p < end; p += 256) {
            int v = bdata[p];
            int pos = atomicAdd(&cur[v & (BSZ - 1)], 1);
            col[pos] = v >> BSHIFT;
        }
    }
}

// ---------- layer 1: h1p = fp16( (x @ W1) * dis[row] ), MFMA hi/lo split ----------
__global__ __launch_bounds__(256) void k_gemm1(const float* __restrict__ x,
                                               const _Float16* __restrict__ wt_hi,
                                               const _Float16* __restrict__ wt_lo,
                                               const float* __restrict__ dis,
                                               _Float16* __restrict__ h1p, int N) {
    __shared__ _Float16 xh[64 * XS], xl[64 * XS], wh[64 * XS], wl[64 * XS];
    int tid = threadIdx.x;
    int row0 = blockIdx.x * 64;
#pragma unroll
    for (int i = 0; i < 8; i++) {
        int idx = i * 256 + tid;          // 2048 float4
        int r = idx >> 5;
        int c = (idx & 31) * 4;
        int rr = row0 + r; if (rr >= N) rr = N - 1;
        float4 v = *(const float4*)(x + (size_t)rr * F + c);
        half4_t h = {(_Float16)v.x, (_Float16)v.y, (_Float16)v.z, (_Float16)v.w};
        half4_t l = {(_Float16)(v.x - (float)h[0]), (_Float16)(v.y - (float)h[1]),
                     (_Float16)(v.z - (float)h[2]), (_Float16)(v.w - (float)h[3])};
        *(half4_t*)(xh + r * XS + c) = h;
        *(half4_t*)(xl + r * XS + c) = l;
    }
#pragma unroll
    for (int i = 0; i < 4; i++) {
        int idx = i * 256 + tid;          // 1024
        int c = idx >> 4;
        int k8 = (idx & 15) * 8;
        *(half8_t*)(wh + c * XS + k8) = *(const half8_t*)(wt_hi + c * 128 + k8);
        *(half8_t*)(wl + c * XS + k8) = *(const half8_t*)(wt_lo + c * 128 + k8);
    }
    __syncthreads();
    int wv = tid >> 6, lane = tid & 63;
    int m = lane & 15, qd = lane >> 4;
    const _Float16* xhp = xh + (wv * 16 + m) * XS;
    const _Float16* xlp = xl + (wv * 16 + m) * XS;
    f32x4 acc[4] = {f32x4{0,0,0,0}, f32x4{0,0,0,0}, f32x4{0,0,0,0}, f32x4{0,0,0,0}};
#pragma unroll
    for (int kc = 0; kc < 4; kc++) {
        int ko = kc * 32 + qd * 8;
        half8_t ah = *(const half8_t*)(xhp + ko);
        half8_t al = *(const half8_t*)(xlp + ko);
#pragma unroll
        for (int nt = 0; nt < 4; nt++) {
            half8_t bh = *(const half8_t*)(wh + (nt * 16 + m) * XS + ko);
            half8_t bl = *(const half8_t*)(wl + (nt * 16 + m) * XS + ko);
            acc[nt] = __builtin_amdgcn_mfma_f32_16x16x32_f16(ah, bh, acc[nt], 0, 0, 0);
            acc[nt] = __builtin_amdgcn_mfma_f32_16x16x32_f16(ah, bl, acc[nt], 0, 0, 0);
            acc[nt] = __builtin_amdgcn_mfma_f32_16x16x32_f16(al, bh, acc[nt], 0, 0, 0);
        }
    }
#pragma unroll
    for (int reg = 0; reg < 4; reg++) {
        int row = row0 + wv * 16 + qd * 4 + reg;
        if (row < N) {
            float d = dis[row];
#pragma unroll
            for (int nt = 0; nt < 4; nt++) {
                h1p[(size_t)row * H + nt * 16 + m] = (_Float16)(acc[nt][reg] * d);
            }
        }
    }
}

// ---------- layer 1 aggregation + fused layer-2 transform ----------
// z = relu(dn*(sum+self)+b1) computed on ALL lanes (butterfly replicates);
// then h2p[node][c] = dn * sum_k z_k W2[k][c] via per-lane partial dots.
__global__ __launch_bounds__(256) void k_gather1(const _Float16* __restrict__ h1p,
                                                 const float* __restrict__ dis,
                                                 const int* __restrict__ row_ptr,
                                                 const int* __restrict__ col,
                                                 const float* __restrict__ b1,
                                                 const float* __restrict__ W2,
                                                 _Float16* __restrict__ h2p, int N) {
    __shared__ float w2t[16 * 65];  // W2^T, stride 65 (bank = (g+8t+j)%32: 2-way, free)
    int tid = threadIdx.x;
    {
        int idx = tid * 4;  // 256 threads x 4 = 1024 = 64*16
        float4 v = *(const float4*)(W2 + idx);
        const float* vp = (const float*)&v;
#pragma unroll
        for (int i = 0; i < 4; i++) {
            int e = idx + i;
            w2t[(e & 15) * 65 + (e >> 4)] = vp[i];
        }
    }
    __syncthreads();
    int node = blockIdx.x * 4 + (tid >> 6);
    int lane = tid & 63;
    int g = lane >> 3;   // edge group / output col 0..7
    int t = lane & 7;    // 8-feature slot
    if (node < N) {
        const half8_t* hp = (const half8_t*)h1p;
        float acc[8];
#pragma unroll
        for (int j = 0; j < 8; j++) acc[j] = 0.f;
        int e = row_ptr[node + 1];
        int p = row_ptr[node] + g;
        for (; p + 8 < e; p += 16) {   // 2 independent row loads in flight per group
            int s0 = col[p], s1 = col[p + 8];
            half8_t v0 = hp[(size_t)s0 * 8 + t];
            half8_t v1 = hp[(size_t)s1 * 8 + t];
#pragma unroll
            for (int j = 0; j < 8; j++) acc[j] += (float)v0[j];
#pragma unroll
            for (int j = 0; j < 8; j++) acc[j] += (float)v1[j];
        }
        if (p < e) {
            int s0 = col[p];
            half8_t v0 = hp[(size_t)s0 * 8 + t];
#pragma unroll
            for (int j = 0; j < 8; j++) acc[j] += (float)v0[j];
        }
#pragma unroll
        for (int off = 8; off < 64; off <<= 1) {
#pragma unroll
            for (int j = 0; j < 8; j++) acc[j] += __shfl_xor(acc[j], off);
        }
        // all lanes now hold full sums for features t*8+j
        float dn = dis[node];
        half8_t self = hp[(size_t)node * 8 + t];
        float o[8];
#pragma unroll
        for (int j = 0; j < 8; j++)
            o[j] = fmaxf(fmaf(acc[j] + (float)self[j], dn, b1[t * 8 + j]), 0.f);
        // fused gemm2: partial dots for c=g and c=g+8
        const float* w1r = w2t + g * 65 + t * 8;
        const float* w2r = w2t + (g + 8) * 65 + t * 8;
        float p1 = 0.f, p2 = 0.f;
#pragma unroll
        for (int j = 0; j < 8; j++) {
            p1 = fmaf(o[j], w1r[j], p1);
            p2 = fmaf(o[j], w2r[j], p2);
        }
#pragma unroll
        for (int off = 1; off < 8; off <<= 1) {
            p1 += __shfl_xor(p1, off);
            p2 += __shfl_xor(p2, off);
        }
        if (t == 0) {
            h2p[(size_t)node * O + g]     = (_Float16)(p1 * dn);
            h2p[(size_t)node * O + g + 8] = (_Float16)(p2 * dn);
        }
    }
}

// ---------- layer 2 aggregation: 1 wave/node, 32 edges in flight, fp16 rows ----------
__global__ __launch_bounds__(256) void k_gather2(const _Float16* __restrict__ h2p,
                                                 const float* __restrict__ dis,
                                                 const int* __restrict__ row_ptr,
                                                 const int* __restrict__ col,
                                                 const float* __restrict__ b2,
                                                 float* __restrict__ z2, int N) {
    int node = blockIdx.x * 4 + (threadIdx.x >> 6);
    if (node >= N) return;
    int lane = threadIdx.x & 63;
    int g = lane >> 1;   // edge group 0..31
    int t = lane & 1;    // 16B slot
    const half8_t* hp = (const half8_t*)h2p;
    float acc[8];
#pragma unroll
    for (int j = 0; j < 8; j++) acc[j] = 0.f;
    int e = row_ptr[node + 1];
    for (int p = row_ptr[node] + g; p < e; p += 32) {
        int s = col[p];
        half8_t v = hp[(size_t)s * 2 + t];
#pragma unroll
        for (int j = 0; j < 8; j++) acc[j] += (float)v[j];
    }
#pragma unroll
    for (int off = 2; off < 64; off <<= 1) {
#pragma unroll
        for (int j = 0; j < 8; j++) acc[j] += __shfl_xor(acc[j], off);
    }
    if (g == 0) {
        float dn = dis[node];
        half8_t self = hp[(size_t)node * 2 + t];
        float o[8];
#pragma unroll
        for (int j = 0; j < 8; j++)
            o[j] = fmaf(acc[j] + (float)self[j], dn, b2[t * 8 + j]);
        float4* zp = (float4*)(z2 + (size_t)node * O + t * 8);
        zp[0] = float4{o[0], o[1], o[2], o[3]};
        zp[1] = float4{o[4], o[5], o[6], o[7]};
    }
}

// ---------- link prediction logits: 4 lanes per pair ----------
__global__ __launch_bounds__(256) void k_logits(const float* __restrict__ z2,
                                                const int* __restrict__ pos,
                                                const int* __restrict__ neg,
                                                float* __restrict__ out, int P, int Q) {
    int tid = blockIdx.x * 256 + threadIdx.x;
    int i = tid >> 2;
    if (i >= P + Q) return;
    int k = tid & 3;
    int a, b;
    if (i < P) { a = pos[i]; b = pos[P + i]; }
    else       { int t = i - P; a = neg[t]; b = neg[Q + t]; }
    float4 va = *(const float4*)(z2 + (size_t)a * O + k * 4);
    float4 vb = *(const float4*)(z2 + (size_t)b * O + k * 4);
    float r = va.x * vb.x + va.y * vb.y + va.z * vb.z + va.w * vb.w;
    r += __shfl_xor(r, 1);
    r += __shfl_xor(r, 2);
    if (k == 0) out[i] = r;
}

extern "C" void kernel_launch(void* const* d_in, const int* in_sizes, int n_in,
                              void* d_out, int out_size, void* d_ws, size_t ws_size,
                              hipStream_t stream) {
    const float* x   = (const float*)d_in[0];
    const int*   ei  = (const int*)d_in[1];
    const int*   pos = (const int*)d_in[2];
    const int*   neg = (const int*)d_in[3];
    const float* W1  = (const float*)d_in[4];
    const float* b1  = (const float*)d_in[5];
    const float* W2  = (const float*)d_in[6];
    const float* b2  = (const float*)d_in[7];
    float* out = (float*)d_out;

    int N = in_sizes[0] / F;
    int E = in_sizes[1] / 2;
    int P = in_sizes[2] / 2;
    int Q = in_sizes[3] / 2;
    const int* src  = ei;
    const int* dstv = ei + E;

    int Npad = ((N + 255) / 256) * 256;
    int Epad = (E + 63) & ~63;
    int NBK = (N + BSZ - 1) / BSZ;    // coarse buckets (782)
    int NC  = NBK * NSUB;             // privatized cursors (12512)

    // workspace layout (byte-exact; bdata aliases h1p — dead before k_gemm1 writes)
    char* w = (char*)d_ws;
    float*    dis     = (float*)w;    w += (size_t)Npad * 4;
    int*      row_ptr = (int*)w;      w += (size_t)(Npad + 256) * 4;
    int*      bcur    = (int*)w;      w += 16384 * 4;          // NC <= 16384
    int*      bstart  = (int*)w;      w += 1024 * 4;
    int*      col     = (int*)w;      w += (size_t)Epad * 4;
    _Float16* h1p     = (_Float16*)w;
    int*      bdata   = (int*)w;
    size_t h1b = (size_t)N * H * 2, bdb = (size_t)NC * SUBCAP * 4;
    w += (h1b > bdb ? h1b : bdb);
    _Float16* h2p     = (_Float16*)w; w += (size_t)N * O * 2;
    float*    z2      = (float*)w;    w += (size_t)N * O * 4;
    _Float16* wt_hi   = (_Float16*)w; w += (size_t)H * F * 2;  // 16KB
    _Float16* wt_lo   = (_Float16*)w;

    int prepN = (NC > H * F) ? NC : H * F;

    // 8 launches total
    k_prep<<<(prepN + 255) / 256, 256, 0, stream>>>(W1, wt_hi, wt_lo, bcur, NC);
    k_bucketA<<<(E + ACHUNK - 1) / ACHUNK, 512, 0, stream>>>(src, dstv, bcur, bdata, E);
    k_bscan<<<1, 1024, 0, stream>>>(bcur, bstart, NBK);
    k_bplace<<<NBK, 256, 0, stream>>>(bdata, bcur, bstart, row_ptr, dis, col, N);

    k_gemm1<<<(N + 63) / 64, 256, 0, stream>>>(x, wt_hi, wt_lo, dis, h1p, N);
    k_gather1<<<(N + 3) / 4, 256, 0, stream>>>(h1p, dis, row_ptr, col, b1, W2, h2p, N);
    k_gather2<<<(N + 3) / 4, 256, 0, stream>>>(h2p, dis, row_ptr, col, b2, z2, N);
    k_logits<<<((P + Q) * 4 + 255) / 256, 256, 0, stream>>>(z2, pos, neg, out, P, Q);
}